// Round 4
// baseline (239.327 us; speedup 1.0000x reference)
//
#include <hip/hip_runtime.h>
#include <hip/hip_bf16.h>

// ---------- types ----------
typedef __attribute__((ext_vector_type(8))) short bf16x8;
typedef __attribute__((ext_vector_type(4))) float f32x4;
typedef __attribute__((ext_vector_type(16))) float f32x16;
typedef __attribute__((ext_vector_type(4))) unsigned u32x4;

#define DEVINL static __device__ __forceinline__
#define GLOBAL_AS __attribute__((address_space(1)))
#define LDS_AS __attribute__((address_space(3)))

DEVINL short f2b(float f) {
  __hip_bfloat16 h = __float2bfloat16(f);
  return __builtin_bit_cast(short, h);
}
DEVINL float b2f(short s) {
  return __bfloat162float(__builtin_bit_cast(__hip_bfloat16, s));
}
// packed f32->bf16 (RNE) : low = a, high = b. One VALU inst.
DEVINL unsigned pack2(float a, float b) {
  unsigned r;
  asm("v_cvt_pk_bf16_f32 %0, %1, %2" : "=v"(r) : "v"(a), "v"(b));
  return r;
}
// dst.hi(lanes 32-63) <-> src.lo(lanes 0-31) exchange, pure VALU
DEVINL void swap32(unsigned& x, unsigned& y) {
  asm("v_permlane32_swap_b32 %0, %1" : "+v"(x), "+v"(y));
}
DEVINL float xhalfsum(float v) {  // v + (v from lane^32)
  float t = v;
  asm("v_permlane32_swap_b32 %0, %1" : "+v"(v), "+v"(t));
  return v + t;
}
DEVINL void load_lds16(const void* g, void* l) {
  __builtin_amdgcn_global_load_lds((const GLOBAL_AS void*)g, (LDS_AS void*)l, 16, 0, 0);
}
DEVINL void barrier_raw() {
  __builtin_amdgcn_sched_barrier(0);
  __builtin_amdgcn_s_barrier();
  __builtin_amdgcn_sched_barrier(0);
}
DEVINL f32x16 mfma32(bf16x8 a, bf16x8 b, f32x16 c) {
  return __builtin_amdgcn_mfma_f32_32x32x16_bf16(a, b, c, 0, 0, 0);
}
DEVINL f32x16 zero16() {
  f32x16 z;
#pragma unroll
  for (int i = 0; i < 16; ++i) z[i] = 0.f;
  return z;
}

// ---------- fused fp32 -> bf16 conversion (x, Wq, Wk, Wv, Wo in one launch) ----------
__global__ __launch_bounds__(256) void cvt_all_kernel(const float* __restrict__ x,
                                                      const float* __restrict__ wq,
                                                      const float* __restrict__ wk,
                                                      const float* __restrict__ wv,
                                                      const float* __restrict__ wo,
                                                      short* __restrict__ xb,
                                                      short* __restrict__ wcat,
                                                      short* __restrict__ wob) {
  int i = blockIdx.x * blockDim.x + threadIdx.x;
  if (i >= 2162688) return;
  const float* src;
  short* dst;
  if (i < 1048576) {
    src = x + (size_t)i * 8;
    dst = xb + (size_t)i * 8;
  } else if (i < 1572864) {
    int j = i - 1048576;
    src = wq + (size_t)j * 8;
    dst = wcat + (size_t)j * 8;
  } else if (i < 1605632) {
    int j = i - 1572864;
    src = wk + (size_t)j * 8;
    dst = wcat + 4194304 + (size_t)j * 8;
  } else if (i < 1638400) {
    int j = i - 1605632;
    src = wv + (size_t)j * 8;
    dst = wcat + 4456448 + (size_t)j * 8;
  } else {
    int j = i - 1638400;
    src = wo + (size_t)j * 8;
    dst = wob + (size_t)j * 8;
  }
  const float4* p = reinterpret_cast<const float4*>(src);
  float4 a = p[0], b = p[1];
  bf16x8 v;
  v[0] = f2b(a.x); v[1] = f2b(a.y); v[2] = f2b(a.z); v[3] = f2b(a.w);
  v[4] = f2b(b.x); v[5] = f2b(b.y); v[6] = f2b(b.z); v[7] = f2b(b.w);
  *reinterpret_cast<bf16x8*>(dst) = v;
}

// ---------- NT GEMM: C[m][n] = sum_k A[m][k]*B[n][k], A [M][K], B [N][K] bf16 ----------
template <int BF16OUT>
__global__ __launch_bounds__(256) void gemm_nt(const short* __restrict__ A,
                                               const short* __restrict__ B,
                                               void* __restrict__ Cv, int M, int N, int K) {
  __shared__ short As[128 * 64];
  __shared__ short Bs[128 * 64];
  const int tid = threadIdx.x;
  const int lane = tid & 63;
  const int wid = tid >> 6;
  const int lr = lane & 15, lg = lane >> 4;
  const int nwg = gridDim.x, cpx = nwg >> 3;
  const int lid = blockIdx.x;
  const int swz = (lid & 7) * cpx + (lid >> 3);
  const int nbn = N >> 7;
  const int bn = swz % nbn, bm = swz / nbn;
  const int wr = wid >> 1, wc = wid & 1;

  f32x4 acc[4][4];
#pragma unroll
  for (int i = 0; i < 4; ++i)
#pragma unroll
    for (int j = 0; j < 4; ++j) acc[i][j] = f32x4{0.f, 0.f, 0.f, 0.f};

  const short* Ag[4];
  const short* Bg[4];
#pragma unroll
  for (int j = 0; j < 4; ++j) {
    int o = j * 4096 + tid * 16;
    int row = o >> 7;
    int src = o ^ ((row & 7) << 4);
    int col = (src & 127) >> 1;
    Ag[j] = A + (size_t)(bm * 128 + row) * K + col;
    Bg[j] = B + (size_t)(bn * 128 + row) * K + col;
  }
  char* Asb = (char*)As;
  char* Bsb = (char*)Bs;
  const int lds_w = wid * 1024;

  for (int kt = 0; kt < K; kt += 64) {
    __syncthreads();
#pragma unroll
    for (int j = 0; j < 4; ++j) load_lds16(Ag[j] + kt, Asb + j * 4096 + lds_w);
#pragma unroll
    for (int j = 0; j < 4; ++j) load_lds16(Bg[j] + kt, Bsb + j * 4096 + lds_w);
    __syncthreads();

#pragma unroll
    for (int kc = 0; kc < 2; ++kc) {
      bf16x8 af[4], bfr[4];
#pragma unroll
      for (int mf = 0; mf < 4; ++mf) {
        int row = wr * 64 + mf * 16 + lr;
        int a_ = (row * 128 + kc * 64 + lg * 16) ^ ((row & 7) << 4);
        af[mf] = *(const bf16x8*)(Asb + a_);
      }
#pragma unroll
      for (int nf = 0; nf < 4; ++nf) {
        int row = wc * 64 + nf * 16 + lr;
        int a_ = (row * 128 + kc * 64 + lg * 16) ^ ((row & 7) << 4);
        bfr[nf] = *(const bf16x8*)(Bsb + a_);
      }
#pragma unroll
      for (int mf = 0; mf < 4; ++mf)
#pragma unroll
        for (int nf = 0; nf < 4; ++nf)
          acc[mf][nf] =
              __builtin_amdgcn_mfma_f32_16x16x32_bf16(af[mf], bfr[nf], acc[mf][nf], 0, 0, 0);
    }
  }

#pragma unroll
  for (int mf = 0; mf < 4; ++mf)
#pragma unroll
    for (int nf = 0; nf < 4; ++nf)
#pragma unroll
      for (int j = 0; j < 4; ++j) {
        int row = bm * 128 + wr * 64 + mf * 16 + lg * 4 + j;
        int col = bn * 128 + wc * 64 + nf * 16 + lr;
        if constexpr (BF16OUT)
          ((short*)Cv)[(size_t)row * N + col] = f2b(acc[mf][nf][j]);
        else
          ((float*)Cv)[(size_t)row * N + col] = acc[mf][nf][j];
      }
}

// ---------- RoPE: qkv [B*T][2304] -> qh [B][H][T][128] (q pre-scaled), kh [B][T][128] ----------
#define QSC 0.031879358f
__global__ __launch_bounds__(256) void rope_kernel(const short* __restrict__ qkv,
                                                   const float* __restrict__ cosb,
                                                   const float* __restrict__ sinb,
                                                   short* __restrict__ qh,
                                                   short* __restrict__ kh) {
  const int bt = blockIdx.x;
  const int b = bt >> 11, t = bt & 2047;
  const int tid = threadIdx.x;
  {
    int h = tid >> 4, d0 = (tid & 15) * 8;
    const short* base = qkv + (size_t)bt * 2304 + h * 128;
    bf16x8 qa = *(const bf16x8*)(base + d0);
    int dp = d0 < 64 ? d0 + 64 : d0 - 64;
    bf16x8 qp = *(const bf16x8*)(base + dp);
    const float* cp = cosb + (size_t)bt * 128 + d0;
    const float* sp = sinb + (size_t)bt * 128 + d0;
    float sgn = d0 < 64 ? -1.f : 1.f;
    bf16x8 r;
#pragma unroll
    for (int e = 0; e < 8; ++e)
      r[e] = f2b((b2f(qa[e]) * cp[e] + sgn * b2f(qp[e]) * sp[e]) * QSC);
    *(bf16x8*)(qh + (((size_t)(b * 16 + h) * 2048 + t) * 128 + d0)) = r;
  }
  if (tid < 16) {
    int d0 = tid * 8;
    const short* base = qkv + (size_t)bt * 2304 + 2048;
    bf16x8 ka = *(const bf16x8*)(base + d0);
    int dp = d0 < 64 ? d0 + 64 : d0 - 64;
    bf16x8 kp = *(const bf16x8*)(base + dp);
    const float* cp = cosb + (size_t)bt * 128 + d0;
    const float* sp = sinb + (size_t)bt * 128 + d0;
    float sgn = d0 < 64 ? -1.f : 1.f;
    bf16x8 r;
#pragma unroll
    for (int e = 0; e < 8; ++e)
      r[e] = f2b(b2f(ka[e]) * cp[e] + sgn * b2f(kp[e]) * sp[e]);
    *(bf16x8*)(kh + ((size_t)bt * 128 + d0)) = r;
  }
}

// ---------- V transpose: qkv v-cols -> vt [B][128][T] ----------
__global__ __launch_bounds__(256) void vtrans_kernel(const short* __restrict__ qkv,
                                                     short* __restrict__ vt) {
  __shared__ short tile[64][33];
  const int tid = threadIdx.x;
  const int t0 = blockIdx.x * 64, d0 = blockIdx.y * 32, b = blockIdx.z;
  {
    int dl = tid & 31, tl0 = tid >> 5;
#pragma unroll
    for (int r = 0; r < 8; ++r) {
      int tl = tl0 + r * 8;
      tile[tl][dl] = qkv[(size_t)(b * 2048 + t0 + tl) * 2304 + 2176 + d0 + dl];
    }
  }
  __syncthreads();
  {
    int dl = tid >> 3, s0 = (tid & 7) * 8;
    bf16x8 v;
#pragma unroll
    for (int e = 0; e < 8; ++e) v[e] = tile[s0 + e][dl];
    *(bf16x8*)(vt + (size_t)(b * 128 + d0 + dl) * 2048 + t0 + s0) = v;
  }
}

// ---------- causal MQA flash attention v13: 64q/wave, shared-frag dual-q, 2 blk/CU ----------
// grid (16, H, B), 128 threads = 2 waves x 64 q-rows (two 32-q halves L/R per wave).
// One 128-q supertile per block; complementary qt map (m/b both pair qt <-> 15-qt) keeps
// either co-residency pattern at ~36 steps/CU. 512 blocks -> 2 independent blocks/CU
// (64 KiB LDS each): one block computes while the other drains vmcnt+barrier.
// KEY CHANGE vs v9-v12 (which all hit the same ~1.75k cyc/wave-step LDS-instr wall):
// each K/V fragment is ds_read ONCE and feeds TWO independent 32-q MFMA chains ->
// LDS read instrs per unit work HALVED, in-wave ILP doubled. Swizzles widened to 16
// slots (K rows 256B: ^((row&15)<<4); Vt packed [64][256B] d-pair rows, same XOR) ->
// 2 lanes/slot = conflict-free (m136: 2-way is free).
// Static-max softmax (Q pre-scaled by 1/sqrt(T)*log2e, P = exp2(S)); all-VALU
// redistribution (cvt_pk + permlane32_swap), v12-proven.
__global__ __launch_bounds__(128) void attn_kernel(const short* __restrict__ qh,
                                                   const short* __restrict__ kh,
                                                   const short* __restrict__ vt,
                                                   short* __restrict__ ao) {
  __shared__ short Ks[2][64 * 128];   // [kv 64][d 128], 256B rows, 16KB/buf
  __shared__ short Vts[2][64 * 128];  // packed: row r'=d>>1 256B = {d=2r' kv0..63 | d=2r'+1}
  const int tid = threadIdx.x, lane = tid & 63, wid = tid >> 6;
  const int c = lane & 31, hi = lane >> 5;
  const int m = blockIdx.x, h = blockIdx.y, b = blockIdx.z;
  // complementary qt map: adjacent m pair low/high; b=0 vs b=1 complement as well
  const int mh = m >> 1;
  const int qt0 = (m & 1) ? (15 - mh) : mh;
  const int qt = b ? (15 - qt0) : qt0;

  // staging source offsets (pre-swizzled; LDS dest stays linear)
  int kof[8], vof[8];
#pragma unroll
  for (int j = 0; j < 8; ++j) {
    int o = tid * 16 + j * 2048;                  // linear LDS byte offset in 16KB buf
    int u = o ^ (((o >> 8) & 15) << 4);           // unswizzled position (involution)
    kof[j] = u;                                   // K: row(kv)*256 + col stays linear
    vof[j] = (u >> 7) * 4096 + (u & 127);         // V: d = u>>7 (global row 4096B), kvl*2
  }
  const char* kgb = (const char*)kh + (size_t)b * 524288;
  const char* vgb = (const char*)vt + (size_t)b * 524288;
  const int ldsu = wid * 1024;  // wave-uniform part of o (lane*16 added by HW)

  auto STAGE = [&](int bufp, int st) {
    char* kd = (char*)Ks[bufp] + ldsu;
    char* vd = (char*)Vts[bufp] + ldsu;
    const char* kgs = kgb + st * (64 * 256);  // s0*256 bytes
    const char* vgs = vgb + st * 128;         // s0*2 bytes
#pragma unroll
    for (int j = 0; j < 8; ++j) load_lds16(kgs + kof[j], kd + j * 2048);
#pragma unroll
    for (int j = 0; j < 8; ++j) load_lds16(vgs + vof[j], vd + j * 2048);
  };

  const int q0 = qt * 128 + wid * 64;  // this wave's 64-q strip base
  const int qvL = q0 + c, qvR = q0 + 32 + c;

  // Q fragments for both 32-q halves (B-operand: lane col=c, k at ki*16+hi*8)
  bf16x8 qfL[8], qfR[8];
  {
    const short* qb = qh + (size_t)(b * 16 + h) * 2048 * 128;
    const short* qbL = qb + (size_t)qvL * 128;
    const short* qbR = qb + (size_t)qvR * 128;
#pragma unroll
    for (int ki = 0; ki < 8; ++ki) {
      qfL[ki] = *(const bf16x8*)(qbL + ki * 16 + hi * 8);
      qfR[ki] = *(const bf16x8*)(qbR + ki * 16 + hi * 8);
    }
  }

  f32x16 OTL[4], OTR[4];
#pragma unroll
  for (int d = 0; d < 4; ++d) {
    OTL[d] = zero16();
    OTR[d] = zero16();
  }
  float lsL = 0.f, lsR = 0.f;

  // softmax on one 32-q half: mask, exp2, row-sum, pack+redistribute -> pf[4]
  auto SMAX = [&](f32x16& C0, f32x16& C1, int q0x, int qvx, float& ls, bf16x8* pf, int s0) {
    if (s0 + 63 > q0x) {
#pragma unroll
      for (int r = 0; r < 16; ++r) {
        int kv0 = s0 + (r & 3) + 8 * (r >> 2) + hi * 4;
        C0[r] = (kv0 > qvx) ? -1e30f : C0[r];
        C1[r] = (kv0 + 32 > qvx) ? -1e30f : C1[r];
      }
    }
    float ps0 = 0.f, ps1 = 0.f, ps2 = 0.f, ps3 = 0.f;
#pragma unroll
    for (int r = 0; r < 16; r += 4) {
      C0[r] = exp2f(C0[r]);          ps0 += C0[r];
      C0[r + 1] = exp2f(C0[r + 1]);  ps1 += C0[r + 1];
      C0[r + 2] = exp2f(C0[r + 2]);  ps2 += C0[r + 2];
      C0[r + 3] = exp2f(C0[r + 3]);  ps3 += C0[r + 3];
    }
#pragma unroll
    for (int r = 0; r < 16; r += 4) {
      C1[r] = exp2f(C1[r]);          ps0 += C1[r];
      C1[r + 1] = exp2f(C1[r + 1]);  ps1 += C1[r + 1];
      C1[r + 2] = exp2f(C1[r + 2]);  ps2 += C1[r + 2];
      C1[r + 3] = exp2f(C1[r + 3]);  ps3 += C1[r + 3];
    }
    ls += xhalfsum((ps0 + ps1) + (ps2 + ps3));

    unsigned D[16];
#pragma unroll
    for (int i = 0; i < 8; ++i) D[i] = pack2(C0[2 * i], C0[2 * i + 1]);
#pragma unroll
    for (int i = 0; i < 8; ++i) D[8 + i] = pack2(C1[2 * i], C1[2 * i + 1]);
#pragma unroll
    for (int ks = 0; ks < 4; ++ks) {
      int bi = ks * 4;
      unsigned a0 = D[bi + 0], a1 = D[bi + 1], a2 = D[bi + 2], a3 = D[bi + 3];
      swap32(a0, a2);
      swap32(a1, a3);
      u32x4 w;
      w[0] = a0; w[1] = a1; w[2] = a2; w[3] = a3;
      pf[ks] = __builtin_bit_cast(bf16x8, w);
    }
  };

  const int n = 2 * qt + 2;  // 64-kv tiles needed for this supertile
  STAGE(0, 0);
  int p = 0;
#pragma unroll 1
  for (int st = 0; st < n; ++st) {
    asm volatile("s_waitcnt vmcnt(0)" ::: "memory");
    barrier_raw();
    if (st + 1 < n) STAGE(p ^ 1, st + 1);
    const int s0 = st * 64;

    if (s0 <= q0 + 63) {  // wave-uniform skip of fully-masked tiles
      const char* Ksb = (const char*)Ks[p];
      const char* Vtb = (const char*)Vts[p];

      // S = K Q^T for both halves; each K fragment read ONCE, used twice
      f32x16 S0L = zero16(), S1L = zero16(), S0R = zero16(), S1R = zero16();
#pragma unroll
      for (int ki = 0; ki < 8; ++ki) {
        int a0 = (c * 256 + ki * 32 + hi * 16) ^ ((c & 15) << 4);
        bf16x8 k0 = *(const bf16x8*)(Ksb + a0);
        bf16x8 k1 = *(const bf16x8*)(Ksb + (a0 + 8192));
        S0L = mfma32(k0, qfL[ki], S0L);
        S1L = mfma32(k1, qfL[ki], S1L);
        S0R = mfma32(k0, qfR[ki], S0R);
        S1R = mfma32(k1, qfR[ki], S1R);
      }

      bf16x8 pfL[4], pfR[4];
      SMAX(S0L, S1L, q0, qvL, lsL, pfL, s0);
      SMAX(S0R, S1R, q0 + 32, qvR, lsR, pfR, s0);

      // O^T += V^T P for both halves; each V fragment read ONCE, used twice
#pragma unroll
      for (int dblk = 0; dblk < 4; ++dblk) {
        int d = dblk * 32 + c;
        int rbase = (d >> 1) * 256 + (d & 1) * 128;
        int sw = ((d >> 1) & 15) << 4;
#pragma unroll
        for (int ks = 0; ks < 4; ++ks) {
          int a_v = (rbase + ks * 32 + hi * 16) ^ sw;
          bf16x8 vf = *(const bf16x8*)(Vtb + a_v);
          OTL[dblk] = mfma32(vf, pfL[ks], OTL[dblk]);
          OTR[dblk] = mfma32(vf, pfR[ks], OTR[dblk]);
        }
      }
    }
    p ^= 1;
  }

  // epilogue: O^T / lsum -> ao[b][q][h][d], paired-d dword stores (both halves)
  {
    float inv = 1.f / lsL;
    short* aob = ao + ((size_t)(b * 2048 + qvL) * 2048 + h * 128);
#pragma unroll
    for (int dblk = 0; dblk < 4; ++dblk) {
#pragma unroll
      for (int rp = 0; rp < 8; ++rp) {
        int r = rp * 2;
        int dd = dblk * 32 + (r & 3) + 8 * (r >> 2) + hi * 4;
        unsigned w = pack2(OTL[dblk][r] * inv, OTL[dblk][r + 1] * inv);
        *(unsigned*)(aob + dd) = w;
      }
    }
  }
  {
    float inv = 1.f / lsR;
    short* aob = ao + ((size_t)(b * 2048 + qvR) * 2048 + h * 128);
#pragma unroll
    for (int dblk = 0; dblk < 4; ++dblk) {
#pragma unroll
      for (int rp = 0; rp < 8; ++rp) {
        int r = rp * 2;
        int dd = dblk * 32 + (r & 3) + 8 * (r >> 2) + hi * 4;
        unsigned w = pack2(OTR[dblk][r] * inv, OTR[dblk][r + 1] * inv);
        *(unsigned*)(aob + dd) = w;
      }
    }
  }
}

// ---------- launch ----------
extern "C" void kernel_launch(void* const* d_in, const int* in_sizes, int n_in,
                              void* d_out, int out_size, void* d_ws, size_t ws_size,
                              hipStream_t stream) {
  const float* x = (const float*)d_in[0];
  const float* cosb = (const float*)d_in[1];
  const float* sinb = (const float*)d_in[2];
  const float* Wq = (const float*)d_in[3];
  const float* Wk = (const float*)d_in[4];
  const float* Wv = (const float*)d_in[5];
  const float* Wo = (const float*)d_in[6];

  char* ws = (char*)d_ws;
  short* xb = (short*)(ws);                    // 16.78 MB  (aliased as ao later)
  short* wcat = (short*)(ws + 16777216);       // 9.44 MB
  short* wob = (short*)(ws + 26214400);        // 8.39 MB
  short* qkv = (short*)(ws + 34603008);        // 18.87 MB
  short* qh = (short*)(ws + 53477376);         // 16.78 MB
  short* kh = (short*)(ws + 70254592);         // 1.05 MB
  short* vt = (short*)(ws + 71303168);         // 1.05 MB
  short* ao = xb;                              // xb dead after gemm1

  cvt_all_kernel<<<8448, 256, 0, stream>>>(x, Wq, Wk, Wv, Wo, xb, wcat, wob);

  gemm_nt<1><<<576, 256, 0, stream>>>(xb, wcat, qkv, 4096, 2304, 2048);
  rope_kernel<<<4096, 256, 0, stream>>>(qkv, cosb, sinb, qh, kh);
  vtrans_kernel<<<dim3(32, 4, 2), 256, 0, stream>>>(qkv, vt);
  attn_kernel<<<dim3(16, 16, 2), 128, 0, stream>>>(qh, kh, vt, ao);
  gemm_nt<0><<<512, 256, 0, stream>>>(ao, wob, d_out, 4096, 2048, 2048);
}